// Round 18
// baseline (564.841 us; speedup 1.0000x reference)
//
#include <hip/hip_runtime.h>
#include <stdint.h>

#define NB 8
#define NSEQ 4096
#define DMODEL 1024
#define NH 16
#define HDIM 64
#define MROWS (NB*NSEQ)      // 32768
#define NCHUNK 128
#define CHUNKL (NSEQ/NCHUNK) // 32
#define MIXROWS 8
#define MIXBLKS (MROWS/MIXROWS)   // 4096

typedef unsigned short u16;
typedef float f32x4 __attribute__((ext_vector_type(4)));
typedef short bf16x8 __attribute__((ext_vector_type(8)));
typedef unsigned short u16x8 __attribute__((ext_vector_type(8)));
typedef unsigned short u16x4 __attribute__((ext_vector_type(4)));

__device__ __forceinline__ u16 f2b(float f) {
  unsigned int u = __builtin_bit_cast(unsigned int, f);
  u = (u + 0x7FFFu + ((u >> 16) & 1u)) >> 16;
  return (u16)u;
}
__device__ __forceinline__ float b2f(u16 s) {
  unsigned int u = ((unsigned int)s) << 16;
  return __builtin_bit_cast(float, u);
}

// async global->LDS, 16B per lane (dest = wave-uniform base + lane*16)
__device__ __forceinline__ void gload16(const void* g, void* l) {
  __builtin_amdgcn_global_load_lds(
      (const __attribute__((address_space(1))) void*)g,
      (__attribute__((address_space(3))) void*)l, 16, 0, 0);
}

// ---------------- prep: mix4 (blocks 0..MIXBLKS-1) + weight cvt ----------------
__global__ __launch_bounds__(256) void prep_kernel(
    const float* __restrict__ X,
    const float* __restrict__ mg, const float* __restrict__ mr,
    const float* __restrict__ mk, const float* __restrict__ mv,
    u16* __restrict__ Ag, u16* __restrict__ Ar, u16* __restrict__ Ak, u16* __restrict__ Av,
    const float* __restrict__ a0, const float* __restrict__ a1,
    const float* __restrict__ a2, const float* __restrict__ a3,
    const float* __restrict__ a4,
    u16* __restrict__ b0, u16* __restrict__ b1, u16* __restrict__ b2,
    u16* __restrict__ b3, u16* __restrict__ b4)
{
  if (blockIdx.x >= MIXBLKS) {
    const int cb = blockIdx.x - MIXBLKS;
    const int mat = cb >> 7;          // 128 blocks per 1M-elem matrix
    const int blk = cb & 127;
    const float* s; u16* d;
    switch (mat) {
      case 0: s = a0; d = b0; break;
      case 1: s = a1; d = b1; break;
      case 2: s = a2; d = b2; break;
      case 3: s = a3; d = b3; break;
      default: s = a4; d = b4; break;
    }
#pragma unroll
    for (int it = 0; it < 8; ++it) {
      const int idx = blk*8192 + it*1024 + threadIdx.x*4;
      const float4 v = *(const float4*)(s + idx);
      u16x4 o; o[0] = f2b(v.x); o[1] = f2b(v.y); o[2] = f2b(v.z); o[3] = f2b(v.w);
      __builtin_nontemporal_store(o, (u16x4*)(d + idx));
    }
    return;
  }

  // mix: 2 row-groups x 128 col-threads, 8 cols/thread; x read once (reg row-carry)
  const int g = threadIdx.x >> 7;
  const int t = threadIdx.x & 127;
  const int c8 = t * 8;
  const int r0 = blockIdx.x * MIXROWS + g * (MIXROWS/2);

  float mgv[8], mrv[8], mkv[8], mvv[8];
  *(float4*)&mgv[0] = *(const float4*)(mg + c8); *(float4*)&mgv[4] = *(const float4*)(mg + c8 + 4);
  *(float4*)&mrv[0] = *(const float4*)(mr + c8); *(float4*)&mrv[4] = *(const float4*)(mr + c8 + 4);
  *(float4*)&mkv[0] = *(const float4*)(mk + c8); *(float4*)&mkv[4] = *(const float4*)(mk + c8 + 4);
  *(float4*)&mvv[0] = *(const float4*)(mv + c8); *(float4*)&mvv[4] = *(const float4*)(mv + c8 + 4);

  const int nidx = r0 & (NSEQ-1);
  const int prow = (nidx == 0) ? r0 + (NSEQ-1) : r0 - 1;  // roll within batch
  float prev[8];
  *(float4*)&prev[0] = *(const float4*)(X + (size_t)prow*DMODEL + c8);
  *(float4*)&prev[4] = *(const float4*)(X + (size_t)prow*DMODEL + c8 + 4);

#pragma unroll
  for (int j = 0; j < MIXROWS/2; ++j) {
    const size_t o = (size_t)(r0 + j)*DMODEL + c8;
    float cur[8];
    *(float4*)&cur[0] = *(const float4*)(X + o);
    *(float4*)&cur[4] = *(const float4*)(X + o + 4);
#define DO_MIX(MV, AP) { \
      bf16x8 s_; \
      _Pragma("unroll") \
      for (int e = 0; e < 8; ++e) s_[e] = (short)f2b(prev[e] + MV[e]*(cur[e]-prev[e])); \
      __builtin_nontemporal_store(s_, (bf16x8*)(AP + o)); }
    DO_MIX(mgv, Ag)
    DO_MIX(mrv, Ar)
    DO_MIX(mkv, Ak)
    DO_MIX(mvv, Av)
#undef DO_MIX
#pragma unroll
    for (int e = 0; e < 8; ++e) prev[e] = cur[e];
  }
}

// ---------------- GEMM 256x256 8-phase, persistent: bx fixed (W L2-hot), walk TPB by-panels ----------------
#define FENCE asm volatile("" ::: "memory")
#define BAR() { FENCE; __builtin_amdgcn_s_barrier(); FENCE; }
#define PRIO1 __builtin_amdgcn_s_setprio(1)
#define PRIO0 __builtin_amdgcn_s_setprio(0)
#define VM6 asm volatile("s_waitcnt vmcnt(6)" ::: "memory")
#define VM4 asm volatile("s_waitcnt vmcnt(4)" ::: "memory")
#define VM0 asm volatile("s_waitcnt vmcnt(0)" ::: "memory")

template<int OUTBF, int NSEG, int TPB>
__global__ __launch_bounds__(512, 2) void gemm256(
    const u16* __restrict__ A0, const u16* __restrict__ W0,
    const float* __restrict__ b0, float* __restrict__ oF0, u16* __restrict__ oB0,
    const u16* __restrict__ A1, const u16* __restrict__ W1,
    const float* __restrict__ b1, float* __restrict__ oF1, u16* __restrict__ oB1)
{
  __shared__ __align__(16) char lds[131072];
  const int tid = threadIdx.x;
  const int wave = tid >> 6, lane = tid & 63;
  const int wm = wave >> 2, wn = wave & 3;       // 2 x 4 waves
  const int rla = lane & 15, kgrp = lane >> 4;

  const int seg = (NSEG == 2) ? ((int)blockIdx.x >> 7) : 0;
  const int wgl = (NSEG == 2) ? ((int)blockIdx.x & 127) : (int)blockIdx.x;
  const u16* Abf = (seg == 0) ? A0 : A1;
  const u16* Wb  = (seg == 0) ? W0 : W1;
  const float* bias = (seg == 0) ? b0 : b1;
  float* outF = (seg == 0) ? oF0 : oF1;
  u16*   outB = (seg == 0) ? oB0 : oB1;

  // T1: XCD swizzle; bx fixed per block, block walks by in [byBase, byBase+TPB)
  const int xcd = wgl & 7;
  const int sub = wgl >> 3;
  const int bx = sub & 3;
  const int byBase = xcd*16 + (sub >> 2) * TPB;

  // staging source offsets (pre-swizzled): F = (wave*2+i)*1024 + lane*16
  const int F0 = (wave*2+0)*1024 + lane*16;
  const int F1 = (wave*2+1)*1024 + lane*16;
  const int r0 = F0 >> 6, r1 = F1 >> 6;
  const int c80 = ((F0 >> 4) & 3) ^ ((r0 >> 1) & 3);
  const int c81 = ((F1 >> 4) & 3) ^ ((r1 >> 1) & 3);
  const char* Ab = (const char*)Abf;
  const char* Bbp = (const char*)Wb;
  const unsigned ga0 = (unsigned)byBase*524288u + r0*2048 + c80*16;
  const unsigned ga1 = (unsigned)byBase*524288u + r1*2048 + c81*16;
  const unsigned gb0 = (unsigned)bx*524288u + r0*2048 + c80*16;
  const unsigned gb1 = (unsigned)bx*524288u + r1*2048 + c81*16;
  const int dst0 = wave*2048;
  const int dst1 = wave*2048 + 1024;

  // bias: tile-invariant (bx fixed)
  float bval[4];
#pragma unroll
  for (int ni = 0; ni < 4; ++ni) bval[ni] = bias[bx*256 + wn*64 + ni*16 + rla];

  f32x4 acc[8][4];
#pragma unroll
  for (int i = 0; i < 8; ++i)
#pragma unroll
    for (int j = 0; j < 4; ++j) acc[i][j] = f32x4{0.f,0.f,0.f,0.f};
  bf16x8 af[8], bfr[4];
  const int lane_ds = rla*64 + ((kgrp ^ ((rla>>1)&3)) << 4);

#define LDS_A(D,KK) (lds + (D)*32768 + (KK)*16384)
#define LDS_B(D,KK) (lds + 65536 + (D)*32768 + (KK)*16384)
#define LDA(D,KK) { _Pragma("unroll") for (int mi_ = 0; mi_ < 8; ++mi_) \
    af[mi_] = *(const bf16x8*)(LDS_A(D,KK) + (wm*128 + mi_*16)*64 + lane_ds); }
#define LDB(P,D,KK) { _Pragma("unroll") for (int j_ = 0; j_ < 2; ++j_) \
    bfr[(P)*2+j_] = *(const bf16x8*)(LDS_B(D,KK) + (wn*64 + ((P)*2+j_)*16)*64 + lane_ds); }
#define MM(P) { _Pragma("unroll") for (int mi_ = 0; mi_ < 8; ++mi_) { \
    acc[mi_][(P)*2+0] = __builtin_amdgcn_mfma_f32_16x16x32_bf16(af[mi_], bfr[(P)*2+0], acc[mi_][(P)*2+0], 0,0,0); \
    acc[mi_][(P)*2+1] = __builtin_amdgcn_mfma_f32_16x16x32_bf16(af[mi_], bfr[(P)*2+1], acc[mi_][(P)*2+1], 0,0,0); } }
// T in [0, TPB*16): B repeats per tile (T&15); A advances tile via (T>>4)*512KiB
#define STAGE(ISB, T, KK) { \
    const char* g_ = (ISB) ? Bbp : Ab; \
    const unsigned tof_ = (ISB) ? ((unsigned)((T)&15)*128u) \
                                : ((unsigned)((T)>>4)*524288u + (unsigned)((T)&15)*128u); \
    const unsigned o0_ = ((ISB) ? gb0 : ga0) + tof_ + (KK)*64; \
    const unsigned o1_ = ((ISB) ? gb1 : ga1) + tof_ + (KK)*64; \
    char* l_ = (ISB) ? LDS_B((T)&1, KK) : LDS_A((T)&1, KK); \
    gload16(g_ + o0_, l_ + dst0); \
    gload16(g_ + o1_, l_ + dst1); }

  // prologue: k-steps 0,1
  STAGE(0, 0, 0); STAGE(1, 0, 0); STAGE(0, 0, 1); STAGE(1, 0, 1);
  VM4;
  STAGE(0, 1, 0); STAGE(1, 1, 0); STAGE(0, 1, 1);
  VM6;
  BAR();

  const int NT = TPB*16;           // total k-steps
#pragma unroll
  for (int tile = 0; tile < TPB; ++tile) {
#pragma unroll 1
    for (int ii = 0; ii < 8; ++ii) {
      const int i = tile*8 + ii;
      const int t1 = 2*i+1, t2 = 2*i+2, t3 = 2*i+3;
      const bool s2 = (t2 < NT);
      // ph1: k-step 2i (buf0) kk0 ni01
      LDA(0,0); LDB(0,0,0); STAGE(1, t1, 1);
      BAR(); PRIO1; MM(0); PRIO0; BAR();
      // ph2: kk0 ni23
      LDB(1,0,0); if (s2) STAGE(0, t2, 0);
      BAR(); PRIO1; MM(1); PRIO0; BAR();
      // ph3: kk1 ni01
      LDA(0,1); LDB(0,0,1); if (s2) STAGE(1, t2, 0);
      BAR(); PRIO1; MM(0); PRIO0; BAR();
      // ph4: kk1 ni23  (+ counted vmcnt guarding k-step 2i+1 reads)
      LDB(1,0,1); if (s2) STAGE(0, t2, 1);
      BAR(); PRIO1; MM(1); PRIO0;
      if (tile == TPB-1 && ii == 7) { VM0; } else { VM6; }
      BAR();
      // ph5: k-step 2i+1 (buf1) kk0 ni01
      LDA(1,0); LDB(0,1,0); if (s2) STAGE(1, t2, 1);
      BAR(); PRIO1; MM(0); PRIO0; BAR();
      // ph6
      LDB(1,1,0); if (s2) STAGE(0, t3, 0);
      BAR(); PRIO1; MM(1); PRIO0; BAR();
      // ph7
      LDA(1,1); LDB(0,1,1); if (s2) STAGE(1, t3, 0);
      BAR(); PRIO1; MM(0); PRIO0; BAR();
      // ph8  (+ counted vmcnt guarding next-iter reads)
      LDB(1,1,1); if (s2) STAGE(0, t3, 1);
      BAR(); PRIO1; MM(1); PRIO0; VM6; BAR();
    }
    // seam epilogue: this tile's by-panel; nontemporal stores (keep W/A L2-resident)
    {
      const int by_ = byBase + tile;
      const int gcb = bx*256 + wn*64 + rla;
#pragma unroll
      for (int mi = 0; mi < 8; ++mi) {
        const int gr0_ = by_*256 + wm*128 + mi*16 + kgrp*4;
#pragma unroll
        for (int q = 0; q < 4; ++q) {
          const size_t rowo = (size_t)(gr0_ + q)*DMODEL;
#pragma unroll
          for (int ni = 0; ni < 4; ++ni) {
            const float v = acc[mi][ni][q] + bval[ni];
            const size_t o = rowo + gcb + ni*16;
            if (OUTBF) __builtin_nontemporal_store(f2b(v), &outB[o]);
            else       __builtin_nontemporal_store(v, &outF[o]);
          }
        }
      }
      if (tile < TPB-1) {
#pragma unroll
        for (int mi = 0; mi < 8; ++mi)
#pragma unroll
          for (int ni = 0; ni < 4; ++ni) acc[mi][ni] = f32x4{0.f,0.f,0.f,0.f};
      }
    }
  }
#undef LDS_A
#undef LDS_B
#undef LDA
#undef LDB
#undef MM
#undef STAGE
}

// ---------------- scan pass 1: chunk-local carry; 8 ch/lane, 16B loads ----------------
__global__ __launch_bounds__(128) void scan_pass1(
    const u16* __restrict__ kbuf, const u16* __restrict__ vbuf,
    const float* __restrict__ w, float* __restrict__ chunkAcc)
{
  const int c = blockIdx.x & (NCHUNK-1);
  const int b = blockIdx.x >> 7;            // NCHUNK=128
  const int hh = threadIdx.x >> 3;          // head 0..15
  const int ch0 = (threadIdx.x & 7) << 3;   // channel base 0..56
  const int hch = hh*HDIM + ch0;

  float dd[8];
#pragma unroll
  for (int j = 0; j < 8; ++j) dd[j] = expf(-expf(w[hch + j]));

  const size_t base = ((size_t)b*NSEQ + (size_t)c*CHUNKL)*DMODEL + hch;
  float acc[8] = {0.f,0.f,0.f,0.f,0.f,0.f,0.f,0.f};
#pragma unroll 4
  for (int i = 0; i < CHUNKL; ++i) {
    const size_t idx = base + (size_t)i*DMODEL;
    const u16x8 k8 = *(const u16x8*)(kbuf + idx);
    const u16x8 v8 = *(const u16x8*)(vbuf + idx);
#pragma unroll
    for (int j = 0; j < 8; ++j)
      acc[j] = dd[j]*acc[j] + b2f(k8[j])*b2f(v8[j]);
  }
  float* cp = &chunkAcc[((size_t)(b*NH + hh)*NCHUNK + c)*HDIM + ch0];
  *(float4*)cp = float4{acc[0], acc[1], acc[2], acc[3]};
  *(float4*)(cp+4) = float4{acc[4], acc[5], acc[6], acc[7]};
}

// ---------------- scan pass 2: combine chunk carries sequentially ----------------
__global__ __launch_bounds__(64) void scan_pass2(
    const float* __restrict__ chunkAcc, float* __restrict__ carryPrev,
    const float* __restrict__ w)
{
  const int bh = blockIdx.x;
  const int h = bh & (NH-1);
  const int lanehd = threadIdx.x;
  const float e = expf(w[h*HDIM + lanehd]);
  const float dL = expf(-e * (float)CHUNKL);   // d^CHUNKL exactly
  const size_t base = (size_t)bh*NCHUNK*HDIM + lanehd;
  float carry = 0.f;
#pragma unroll 4
  for (int c = 0; c < NCHUNK; ++c) {
    carryPrev[base + (size_t)c*HDIM] = carry;  // acc entering chunk c
    carry = chunkAcc[base + (size_t)c*HDIM] + dL*carry;
  }
}

// ---------------- scan pass 3: rescan + carry + u*kv + r* + LN + gate -> h(bf16); 8 ch/lane ----------------
__global__ __launch_bounds__(128) void scan_pass3(
    const u16* __restrict__ kbuf, const u16* __restrict__ vbuf,
    const u16* __restrict__ rbuf, const u16* __restrict__ gbuf,
    u16* __restrict__ hbuf, const float* __restrict__ carryPrev,
    const float* __restrict__ w, const float* __restrict__ u)
{
  const int c = blockIdx.x & (NCHUNK-1);
  const int b = blockIdx.x >> 7;
  const int hh = threadIdx.x >> 3;
  const int ch0 = (threadIdx.x & 7) << 3;
  const int hch = hh*HDIM + ch0;

  float dd[8], uv[8], carry[8], fac[8], acc[8];
#pragma unroll
  for (int j = 0; j < 8; ++j) {
    dd[j] = expf(-expf(w[hch + j]));
    uv[j] = u[hch + j];
    fac[j] = dd[j];
    acc[j] = 0.f;
  }
  {
    const float* cp = &carryPrev[((size_t)(b*NH + hh)*NCHUNK + c)*HDIM + ch0];
    const float4 c0 = *(const float4*)cp;
    const float4 c1 = *(const float4*)(cp+4);
    carry[0]=c0.x; carry[1]=c0.y; carry[2]=c0.z; carry[3]=c0.w;
    carry[4]=c1.x; carry[5]=c1.y; carry[6]=c1.z; carry[7]=c1.w;
  }

  const size_t base = ((size_t)b*NSEQ + (size_t)c*CHUNKL)*DMODEL + hch;
#pragma unroll 2
  for (int i = 0; i < CHUNKL; ++i) {
    const size_t idx = base + (size_t)i*DMODEL;
    const u16x8 k8 = *(const u16x8*)(kbuf + idx);
    const u16x8 v8 = *(const u16x8*)(vbuf + idx);
    const u16x8 r8 = *(const u16x8*)(rbuf + idx);
    const u16x8 g8 = *(const u16x8*)(gbuf + idx);
    float rw[8];
    float s1 = 0.f, s2 = 0.f;
#pragma unroll
    for (int j = 0; j < 8; ++j) {
      const float kv = b2f(k8[j])*b2f(v8[j]);
      acc[j] = dd[j]*acc[j] + kv;
      const float wkv = acc[j] + fac[j]*carry[j] + uv[j]*kv;
      fac[j] *= dd[j];
      rw[j] = b2f(r8[j])*wkv;
      s1 += rw[j]; s2 += rw[j]*rw[j];
    }
    // LN reduce over the 8-lane group (64 channels)
#pragma unroll
    for (int off = 4; off >= 1; off >>= 1) {
      s1 += __shfl_xor(s1, off);
      s2 += __shfl_xor(s2, off);
    }
    const float mean = s1 * (1.f/64.f);
    const float var = s2 * (1.f/64.f) - mean*mean;
    const float rstd = rsqrtf(var + 1e-5f);
    u16x8 o;
#pragma unroll
    for (int j = 0; j < 8; ++j)
      o[j] = f2b((rw[j]-mean)*rstd * (1.f/(1.f+expf(-b2f(g8[j])))));
    __builtin_nontemporal_store(o, (u16x8*)(hbuf + idx));
  }
}

// ---------------- launch ----------------
extern "C" void kernel_launch(void* const* d_in, const int* in_sizes, int n_in,
                              void* d_out, int out_size, void* d_ws, size_t ws_size,
                              hipStream_t stream)
{
  const float* x   = (const float*)d_in[0];
  const float* WgW = (const float*)d_in[1];
  const float* Wgb = (const float*)d_in[2];
  const float* WrW = (const float*)d_in[3];
  const float* Wrb = (const float*)d_in[4];
  const float* WkW = (const float*)d_in[5];
  const float* Wkb = (const float*)d_in[6];
  const float* WvW = (const float*)d_in[7];
  const float* Wvb = (const float*)d_in[8];
  const float* WoW = (const float*)d_in[9];
  const float* Wob = (const float*)d_in[10];
  const float* mg  = (const float*)d_in[11];
  const float* mr  = (const float*)d_in[12];
  const float* mk  = (const float*)d_in[13];
  const float* mv  = (const float*)d_in[14];
  const float* w   = (const float*)d_in[15];
  const float* u   = (const float*)d_in[16];
  char* ws = (char*)d_ws;

  const size_t WBB = (size_t)DMODEL*DMODEL*2;   // 2 MiB
  u16* WgB = (u16*)(ws + 0*WBB);
  u16* WrB = (u16*)(ws + 1*WBB);
  u16* WkB = (u16*)(ws + 2*WBB);
  u16* WvB = (u16*)(ws + 3*WBB);
  u16* WoB = (u16*)(ws + 4*WBB);
  size_t off = 5*WBB;
  const size_t EL = (size_t)MROWS*DMODEL;       // 33.5M elements

  // Am slots (4 x 64MiB bf16). Consumption order allows aliasing:
  //   kbuf -> Amg slot (k GEMM runs after g consumed Amg), vbuf -> Amr, hbuf -> Amk.
  char* amBase = ws + off;
  u16* Amg = (u16*)(amBase);
  u16* Amr = (u16*)(amBase + EL*2);
  u16* Amk = (u16*)(amBase + EL*4);
  u16* Amv = (u16*)(amBase + EL*6);
  u16* kbuf = Amg;
  u16* vbuf = Amr;
  u16* hbuf = Amk;
  off += EL*8;
  u16* gbuf = (u16*)(ws + off);   off += EL*2;
  u16* rbuf = (u16*)(ws + off);   off += EL*2;
  float* chunkAcc  = (float*)(ws + off); off += (size_t)NB*NH*NCHUNK*HDIM*4;
  float* carryPrev = (float*)(ws + off); off += (size_t)NB*NH*NCHUNK*HDIM*4;

  prep_kernel<<<MIXBLKS + 640, 256, 0, stream>>>(
      x, mg, mr, mk, mv, Amg, Amr, Amk, Amv,
      WgW, WrW, WkW, WvW, WoW, WgB, WrB, WkB, WvB, WoB);

  // persistent pair launches: 256 blocks, bx fixed, 4 by-panels/block, 1 round
  gemm256<1,2,4><<<256, 512, 0, stream>>>(Amg, WgB, Wgb, nullptr, gbuf,
                                          Amr, WrB, Wrb, nullptr, rbuf);
  gemm256<1,2,4><<<256, 512, 0, stream>>>(Amk, WkB, Wkb, nullptr, kbuf,
                                          Amv, WvB, Wvb, nullptr, vbuf);

  scan_pass1<<<NB*NCHUNK, 128, 0, stream>>>(kbuf, vbuf, w, chunkAcc);
  scan_pass2<<<NB*NH, 64, 0, stream>>>(chunkAcc, carryPrev, w);
  scan_pass3<<<NB*NCHUNK, 128, 0, stream>>>(kbuf, vbuf, rbuf, gbuf, hbuf, carryPrev, w, u);

  // persistent final GEMM: 256 blocks, 2 by-panels/block, 1 round
  gemm256<0,1,2><<<256, 512, 0, stream>>>(hbuf, WoB, Wob, (float*)d_out, nullptr,
                                          nullptr, nullptr, nullptr, nullptr, nullptr);
}

// Round 19
// 533.515 us; speedup vs baseline: 1.0587x; 1.0587x over previous
//
#include <hip/hip_runtime.h>
#include <stdint.h>

#define NB 8
#define NSEQ 4096
#define DMODEL 1024
#define NH 16
#define HDIM 64
#define MROWS (NB*NSEQ)      // 32768
#define NCHUNK 128
#define CHUNKL (NSEQ/NCHUNK) // 32
#define MIXROWS 8
#define MIXBLKS (MROWS/MIXROWS)   // 4096

typedef unsigned short u16;
typedef float f32x4 __attribute__((ext_vector_type(4)));
typedef short bf16x8 __attribute__((ext_vector_type(8)));
typedef unsigned short u16x8 __attribute__((ext_vector_type(8)));

__device__ __forceinline__ u16 f2b(float f) {
  unsigned int u = __builtin_bit_cast(unsigned int, f);
  u = (u + 0x7FFFu + ((u >> 16) & 1u)) >> 16;
  return (u16)u;
}
__device__ __forceinline__ float b2f(u16 s) {
  unsigned int u = ((unsigned int)s) << 16;
  return __builtin_bit_cast(float, u);
}

// async global->LDS, 16B per lane (dest = wave-uniform base + lane*16)
__device__ __forceinline__ void gload16(const void* g, void* l) {
  __builtin_amdgcn_global_load_lds(
      (const __attribute__((address_space(1))) void*)g,
      (__attribute__((address_space(3))) void*)l, 16, 0, 0);
}

// ---------------- prep: mix4 (blocks 0..MIXBLKS-1) + weight cvt ----------------
__global__ __launch_bounds__(256) void prep_kernel(
    const float* __restrict__ X,
    const float* __restrict__ mg, const float* __restrict__ mr,
    const float* __restrict__ mk, const float* __restrict__ mv,
    u16* __restrict__ Ag, u16* __restrict__ Ar, u16* __restrict__ Ak, u16* __restrict__ Av,
    const float* __restrict__ a0, const float* __restrict__ a1,
    const float* __restrict__ a2, const float* __restrict__ a3,
    const float* __restrict__ a4,
    u16* __restrict__ b0, u16* __restrict__ b1, u16* __restrict__ b2,
    u16* __restrict__ b3, u16* __restrict__ b4)
{
  if (blockIdx.x >= MIXBLKS) {
    const int cb = blockIdx.x - MIXBLKS;
    const int mat = cb >> 7;          // 128 blocks per 1M-elem matrix
    const int blk = cb & 127;
    const float* s; u16* d;
    switch (mat) {
      case 0: s = a0; d = b0; break;
      case 1: s = a1; d = b1; break;
      case 2: s = a2; d = b2; break;
      case 3: s = a3; d = b3; break;
      default: s = a4; d = b4; break;
    }
#pragma unroll
    for (int it = 0; it < 8; ++it) {
      const int idx = blk*8192 + it*1024 + threadIdx.x*4;
      const float4 v = *(const float4*)(s + idx);
      ushort4 o; o.x = f2b(v.x); o.y = f2b(v.y); o.z = f2b(v.z); o.w = f2b(v.w);
      *(ushort4*)(d + idx) = o;
    }
    return;
  }

  // mix: 2 row-groups x 128 col-threads, 8 cols/thread; x read once (reg row-carry)
  const int g = threadIdx.x >> 7;
  const int t = threadIdx.x & 127;
  const int c8 = t * 8;
  const int r0 = blockIdx.x * MIXROWS + g * (MIXROWS/2);

  float mgv[8], mrv[8], mkv[8], mvv[8];
  *(float4*)&mgv[0] = *(const float4*)(mg + c8); *(float4*)&mgv[4] = *(const float4*)(mg + c8 + 4);
  *(float4*)&mrv[0] = *(const float4*)(mr + c8); *(float4*)&mrv[4] = *(const float4*)(mr + c8 + 4);
  *(float4*)&mkv[0] = *(const float4*)(mk + c8); *(float4*)&mkv[4] = *(const float4*)(mk + c8 + 4);
  *(float4*)&mvv[0] = *(const float4*)(mv + c8); *(float4*)&mvv[4] = *(const float4*)(mv + c8 + 4);

  const int nidx = r0 & (NSEQ-1);
  const int prow = (nidx == 0) ? r0 + (NSEQ-1) : r0 - 1;  // roll within batch
  float prev[8];
  *(float4*)&prev[0] = *(const float4*)(X + (size_t)prow*DMODEL + c8);
  *(float4*)&prev[4] = *(const float4*)(X + (size_t)prow*DMODEL + c8 + 4);

#pragma unroll
  for (int j = 0; j < MIXROWS/2; ++j) {
    const size_t o = (size_t)(r0 + j)*DMODEL + c8;
    float cur[8];
    *(float4*)&cur[0] = *(const float4*)(X + o);
    *(float4*)&cur[4] = *(const float4*)(X + o + 4);
#define DO_MIX(MV, AP) { \
      bf16x8 s_; \
      _Pragma("unroll") \
      for (int e = 0; e < 8; ++e) s_[e] = (short)f2b(prev[e] + MV[e]*(cur[e]-prev[e])); \
      *(bf16x8*)(AP + o) = s_; }
    DO_MIX(mgv, Ag)
    DO_MIX(mrv, Ar)
    DO_MIX(mkv, Ak)
    DO_MIX(mvv, Av)
#undef DO_MIX
#pragma unroll
    for (int e = 0; e < 8; ++e) prev[e] = cur[e];
  }
}

// ---------------- GEMM 256x256 8-phase, persistent: bx fixed (W L2-hot), walk TPB by-panels ----------------
#define FENCE asm volatile("" ::: "memory")
#define BAR() { FENCE; __builtin_amdgcn_s_barrier(); FENCE; }
#define PRIO1 __builtin_amdgcn_s_setprio(1)
#define PRIO0 __builtin_amdgcn_s_setprio(0)
#define VM6 asm volatile("s_waitcnt vmcnt(6)" ::: "memory")
#define VM4 asm volatile("s_waitcnt vmcnt(4)" ::: "memory")
#define VM0 asm volatile("s_waitcnt vmcnt(0)" ::: "memory")

template<int OUTBF, int NSEG, int TPB>
__global__ __launch_bounds__(512, 2) void gemm256(
    const u16* __restrict__ A0, const u16* __restrict__ W0,
    const float* __restrict__ b0, float* __restrict__ oF0, u16* __restrict__ oB0,
    const u16* __restrict__ A1, const u16* __restrict__ W1,
    const float* __restrict__ b1, float* __restrict__ oF1, u16* __restrict__ oB1)
{
  __shared__ __align__(16) char lds[131072];
  const int tid = threadIdx.x;
  const int wave = tid >> 6, lane = tid & 63;
  const int wm = wave >> 2, wn = wave & 3;       // 2 x 4 waves
  const int rla = lane & 15, kgrp = lane >> 4;

  const int seg = (NSEG == 2) ? ((int)blockIdx.x >> 7) : 0;
  const int wgl = (NSEG == 2) ? ((int)blockIdx.x & 127) : (int)blockIdx.x;
  const u16* Abf = (seg == 0) ? A0 : A1;
  const u16* Wb  = (seg == 0) ? W0 : W1;
  const float* bias = (seg == 0) ? b0 : b1;
  float* outF = (seg == 0) ? oF0 : oF1;
  u16*   outB = (seg == 0) ? oB0 : oB1;

  // T1: XCD swizzle; bx fixed per block, block walks by in [byBase, byBase+TPB)
  const int xcd = wgl & 7;
  const int sub = wgl >> 3;
  const int bx = sub & 3;
  const int byBase = xcd*16 + (sub >> 2) * TPB;

  // staging source offsets (pre-swizzled): F = (wave*2+i)*1024 + lane*16
  const int F0 = (wave*2+0)*1024 + lane*16;
  const int F1 = (wave*2+1)*1024 + lane*16;
  const int r0 = F0 >> 6, r1 = F1 >> 6;
  const int c80 = ((F0 >> 4) & 3) ^ ((r0 >> 1) & 3);
  const int c81 = ((F1 >> 4) & 3) ^ ((r1 >> 1) & 3);
  const char* Ab = (const char*)Abf;
  const char* Bbp = (const char*)Wb;
  const unsigned ga0 = (unsigned)byBase*524288u + r0*2048 + c80*16;
  const unsigned ga1 = (unsigned)byBase*524288u + r1*2048 + c81*16;
  const unsigned gb0 = (unsigned)bx*524288u + r0*2048 + c80*16;
  const unsigned gb1 = (unsigned)bx*524288u + r1*2048 + c81*16;
  const int dst0 = wave*2048;
  const int dst1 = wave*2048 + 1024;

  // bias: tile-invariant (bx fixed)
  float bval[4];
#pragma unroll
  for (int ni = 0; ni < 4; ++ni) bval[ni] = bias[bx*256 + wn*64 + ni*16 + rla];

  f32x4 acc[8][4];
#pragma unroll
  for (int i = 0; i < 8; ++i)
#pragma unroll
    for (int j = 0; j < 4; ++j) acc[i][j] = f32x4{0.f,0.f,0.f,0.f};
  bf16x8 af[8], bfr[4];
  const int lane_ds = rla*64 + ((kgrp ^ ((rla>>1)&3)) << 4);

#define LDS_A(D,KK) (lds + (D)*32768 + (KK)*16384)
#define LDS_B(D,KK) (lds + 65536 + (D)*32768 + (KK)*16384)
#define LDA(D,KK) { _Pragma("unroll") for (int mi_ = 0; mi_ < 8; ++mi_) \
    af[mi_] = *(const bf16x8*)(LDS_A(D,KK) + (wm*128 + mi_*16)*64 + lane_ds); }
#define LDB(P,D,KK) { _Pragma("unroll") for (int j_ = 0; j_ < 2; ++j_) \
    bfr[(P)*2+j_] = *(const bf16x8*)(LDS_B(D,KK) + (wn*64 + ((P)*2+j_)*16)*64 + lane_ds); }
#define MM(P) { _Pragma("unroll") for (int mi_ = 0; mi_ < 8; ++mi_) { \
    acc[mi_][(P)*2+0] = __builtin_amdgcn_mfma_f32_16x16x32_bf16(af[mi_], bfr[(P)*2+0], acc[mi_][(P)*2+0], 0,0,0); \
    acc[mi_][(P)*2+1] = __builtin_amdgcn_mfma_f32_16x16x32_bf16(af[mi_], bfr[(P)*2+1], acc[mi_][(P)*2+1], 0,0,0); } }
// T in [0, TPB*16): B repeats per tile (T&15); A advances tile via (T>>4)*512KiB
#define STAGE(ISB, T, KK) { \
    const char* g_ = (ISB) ? Bbp : Ab; \
    const unsigned tof_ = (ISB) ? ((unsigned)((T)&15)*128u) \
                                : ((unsigned)((T)>>4)*524288u + (unsigned)((T)&15)*128u); \
    const unsigned o0_ = ((ISB) ? gb0 : ga0) + tof_ + (KK)*64; \
    const unsigned o1_ = ((ISB) ? gb1 : ga1) + tof_ + (KK)*64; \
    char* l_ = (ISB) ? LDS_B((T)&1, KK) : LDS_A((T)&1, KK); \
    gload16(g_ + o0_, l_ + dst0); \
    gload16(g_ + o1_, l_ + dst1); }

  // prologue: k-steps 0,1
  STAGE(0, 0, 0); STAGE(1, 0, 0); STAGE(0, 0, 1); STAGE(1, 0, 1);
  VM4;
  STAGE(0, 1, 0); STAGE(1, 1, 0); STAGE(0, 1, 1);
  VM6;
  BAR();

  const int NT = TPB*16;           // total k-steps
#pragma unroll
  for (int tile = 0; tile < TPB; ++tile) {
#pragma unroll 1
    for (int ii = 0; ii < 8; ++ii) {
      const int i = tile*8 + ii;
      const int t1 = 2*i+1, t2 = 2*i+2, t3 = 2*i+3;
      const bool s2 = (t2 < NT);
      // ph1: k-step 2i (buf0) kk0 ni01
      LDA(0,0); LDB(0,0,0); STAGE(1, t1, 1);
      BAR(); PRIO1; MM(0); PRIO0; BAR();
      // ph2: kk0 ni23
      LDB(1,0,0); if (s2) STAGE(0, t2, 0);
      BAR(); PRIO1; MM(1); PRIO0; BAR();
      // ph3: kk1 ni01
      LDA(0,1); LDB(0,0,1); if (s2) STAGE(1, t2, 0);
      BAR(); PRIO1; MM(0); PRIO0; BAR();
      // ph4: kk1 ni23  (+ counted vmcnt guarding k-step 2i+1 reads)
      LDB(1,0,1); if (s2) STAGE(0, t2, 1);
      BAR(); PRIO1; MM(1); PRIO0;
      if (tile == TPB-1 && ii == 7) { VM0; } else { VM6; }
      BAR();
      // ph5: k-step 2i+1 (buf1) kk0 ni01
      LDA(1,0); LDB(0,1,0); if (s2) STAGE(1, t2, 1);
      BAR(); PRIO1; MM(0); PRIO0; BAR();
      // ph6
      LDB(1,1,0); if (s2) STAGE(0, t3, 0);
      BAR(); PRIO1; MM(1); PRIO0; BAR();
      // ph7
      LDA(1,1); LDB(0,1,1); if (s2) STAGE(1, t3, 0);
      BAR(); PRIO1; MM(0); PRIO0; BAR();
      // ph8  (+ counted vmcnt guarding next-iter reads)
      LDB(1,1,1); if (s2) STAGE(0, t3, 1);
      BAR(); PRIO1; MM(1); PRIO0; VM6; BAR();
    }
    // seam epilogue: this tile's by-panel; stores drain during next tile's phases
    {
      const int by_ = byBase + tile;
      const int gcb = bx*256 + wn*64 + rla;
#pragma unroll
      for (int mi = 0; mi < 8; ++mi) {
        const int gr0_ = by_*256 + wm*128 + mi*16 + kgrp*4;
#pragma unroll
        for (int q = 0; q < 4; ++q) {
          const size_t rowo = (size_t)(gr0_ + q)*DMODEL;
#pragma unroll
          for (int ni = 0; ni < 4; ++ni) {
            const float v = acc[mi][ni][q] + bval[ni];
            const size_t o = rowo + gcb + ni*16;
            if (OUTBF) outB[o] = f2b(v);
            else       outF[o] = v;
          }
        }
      }
      if (tile < TPB-1) {
#pragma unroll
        for (int mi = 0; mi < 8; ++mi)
#pragma unroll
          for (int ni = 0; ni < 4; ++ni) acc[mi][ni] = f32x4{0.f,0.f,0.f,0.f};
      }
    }
  }
#undef LDS_A
#undef LDS_B
#undef LDA
#undef LDB
#undef MM
#undef STAGE
}

// ---------------- scan pass 1: chunk-local carry; 8 ch/lane, 16B loads ----------------
__global__ __launch_bounds__(128) void scan_pass1(
    const u16* __restrict__ kbuf, const u16* __restrict__ vbuf,
    const float* __restrict__ w, float* __restrict__ chunkAcc)
{
  const int c = blockIdx.x & (NCHUNK-1);
  const int b = blockIdx.x >> 7;            // NCHUNK=128
  const int hh = threadIdx.x >> 3;          // head 0..15
  const int ch0 = (threadIdx.x & 7) << 3;   // channel base 0..56
  const int hch = hh*HDIM + ch0;

  float dd[8];
#pragma unroll
  for (int j = 0; j < 8; ++j) dd[j] = expf(-expf(w[hch + j]));

  const size_t base = ((size_t)b*NSEQ + (size_t)c*CHUNKL)*DMODEL + hch;
  float acc[8] = {0.f,0.f,0.f,0.f,0.f,0.f,0.f,0.f};
#pragma unroll 4
  for (int i = 0; i < CHUNKL; ++i) {
    const size_t idx = base + (size_t)i*DMODEL;
    const u16x8 k8 = *(const u16x8*)(kbuf + idx);
    const u16x8 v8 = *(const u16x8*)(vbuf + idx);
#pragma unroll
    for (int j = 0; j < 8; ++j)
      acc[j] = dd[j]*acc[j] + b2f(k8[j])*b2f(v8[j]);
  }
  float* cp = &chunkAcc[((size_t)(b*NH + hh)*NCHUNK + c)*HDIM + ch0];
  *(float4*)cp = float4{acc[0], acc[1], acc[2], acc[3]};
  *(float4*)(cp+4) = float4{acc[4], acc[5], acc[6], acc[7]};
}

// ---------------- scan pass 2: combine chunk carries sequentially ----------------
__global__ __launch_bounds__(64) void scan_pass2(
    const float* __restrict__ chunkAcc, float* __restrict__ carryPrev,
    const float* __restrict__ w)
{
  const int bh = blockIdx.x;
  const int h = bh & (NH-1);
  const int lanehd = threadIdx.x;
  const float e = expf(w[h*HDIM + lanehd]);
  const float dL = expf(-e * (float)CHUNKL);   // d^CHUNKL exactly
  const size_t base = (size_t)bh*NCHUNK*HDIM + lanehd;
  float carry = 0.f;
#pragma unroll 4
  for (int c = 0; c < NCHUNK; ++c) {
    carryPrev[base + (size_t)c*HDIM] = carry;  // acc entering chunk c
    carry = chunkAcc[base + (size_t)c*HDIM] + dL*carry;
  }
}

// ---------------- scan pass 3: rescan + carry + u*kv + r* + LN + gate -> h(bf16); 8 ch/lane ----------------
__global__ __launch_bounds__(128) void scan_pass3(
    const u16* __restrict__ kbuf, const u16* __restrict__ vbuf,
    const u16* __restrict__ rbuf, const u16* __restrict__ gbuf,
    u16* __restrict__ hbuf, const float* __restrict__ carryPrev,
    const float* __restrict__ w, const float* __restrict__ u)
{
  const int c = blockIdx.x & (NCHUNK-1);
  const int b = blockIdx.x >> 7;
  const int hh = threadIdx.x >> 3;
  const int ch0 = (threadIdx.x & 7) << 3;
  const int hch = hh*HDIM + ch0;

  float dd[8], uv[8], carry[8], fac[8], acc[8];
#pragma unroll
  for (int j = 0; j < 8; ++j) {
    dd[j] = expf(-expf(w[hch + j]));
    uv[j] = u[hch + j];
    fac[j] = dd[j];
    acc[j] = 0.f;
  }
  {
    const float* cp = &carryPrev[((size_t)(b*NH + hh)*NCHUNK + c)*HDIM + ch0];
    const float4 c0 = *(const float4*)cp;
    const float4 c1 = *(const float4*)(cp+4);
    carry[0]=c0.x; carry[1]=c0.y; carry[2]=c0.z; carry[3]=c0.w;
    carry[4]=c1.x; carry[5]=c1.y; carry[6]=c1.z; carry[7]=c1.w;
  }

  const size_t base = ((size_t)b*NSEQ + (size_t)c*CHUNKL)*DMODEL + hch;
#pragma unroll 2
  for (int i = 0; i < CHUNKL; ++i) {
    const size_t idx = base + (size_t)i*DMODEL;
    const u16x8 k8 = *(const u16x8*)(kbuf + idx);
    const u16x8 v8 = *(const u16x8*)(vbuf + idx);
    const u16x8 r8 = *(const u16x8*)(rbuf + idx);
    const u16x8 g8 = *(const u16x8*)(gbuf + idx);
    float rw[8];
    float s1 = 0.f, s2 = 0.f;
#pragma unroll
    for (int j = 0; j < 8; ++j) {
      const float kv = b2f(k8[j])*b2f(v8[j]);
      acc[j] = dd[j]*acc[j] + kv;
      const float wkv = acc[j] + fac[j]*carry[j] + uv[j]*kv;
      fac[j] *= dd[j];
      rw[j] = b2f(r8[j])*wkv;
      s1 += rw[j]; s2 += rw[j]*rw[j];
    }
    // LN reduce over the 8-lane group (64 channels)
#pragma unroll
    for (int off = 4; off >= 1; off >>= 1) {
      s1 += __shfl_xor(s1, off);
      s2 += __shfl_xor(s2, off);
    }
    const float mean = s1 * (1.f/64.f);
    const float var = s2 * (1.f/64.f) - mean*mean;
    const float rstd = rsqrtf(var + 1e-5f);
    u16x8 o;
#pragma unroll
    for (int j = 0; j < 8; ++j)
      o[j] = f2b((rw[j]-mean)*rstd * (1.f/(1.f+expf(-b2f(g8[j])))));
    *(u16x8*)(hbuf + idx) = o;
  }
}

// ---------------- launch ----------------
extern "C" void kernel_launch(void* const* d_in, const int* in_sizes, int n_in,
                              void* d_out, int out_size, void* d_ws, size_t ws_size,
                              hipStream_t stream)
{
  const float* x   = (const float*)d_in[0];
  const float* WgW = (const float*)d_in[1];
  const float* Wgb = (const float*)d_in[2];
  const float* WrW = (const float*)d_in[3];
  const float* Wrb = (const float*)d_in[4];
  const float* WkW = (const float*)d_in[5];
  const float* Wkb = (const float*)d_in[6];
  const float* WvW = (const float*)d_in[7];
  const float* Wvb = (const float*)d_in[8];
  const float* WoW = (const float*)d_in[9];
  const float* Wob = (const float*)d_in[10];
  const float* mg  = (const float*)d_in[11];
  const float* mr  = (const float*)d_in[12];
  const float* mk  = (const float*)d_in[13];
  const float* mv  = (const float*)d_in[14];
  const float* w   = (const float*)d_in[15];
  const float* u   = (const float*)d_in[16];
  char* ws = (char*)d_ws;

  const size_t WBB = (size_t)DMODEL*DMODEL*2;   // 2 MiB
  u16* WgB = (u16*)(ws + 0*WBB);
  u16* WrB = (u16*)(ws + 1*WBB);
  u16* WkB = (u16*)(ws + 2*WBB);
  u16* WvB = (u16*)(ws + 3*WBB);
  u16* WoB = (u16*)(ws + 4*WBB);
  size_t off = 5*WBB;
  const size_t EL = (size_t)MROWS*DMODEL;       // 33.5M elements

  // Am slots (4 x 64MiB bf16). Consumption order allows aliasing:
  //   kbuf -> Amg slot (k GEMM runs after g consumed Amg), vbuf -> Amr, hbuf -> Amk.
  char* amBase = ws + off;
  u16* Amg = (u16*)(amBase);
  u16* Amr = (u16*)(amBase + EL*2);
  u16* Amk = (u16*)(amBase + EL*4);
  u16* Amv = (u16*)(amBase + EL*6);
  u16* kbuf = Amg;
  u16* vbuf = Amr;
  u16* hbuf = Amk;
  off += EL*8;
  u16* gbuf = (u16*)(ws + off);   off += EL*2;
  u16* rbuf = (u16*)(ws + off);   off += EL*2;
  float* chunkAcc  = (float*)(ws + off); off += (size_t)NB*NH*NCHUNK*HDIM*4;
  float* carryPrev = (float*)(ws + off); off += (size_t)NB*NH*NCHUNK*HDIM*4;

  prep_kernel<<<MIXBLKS + 640, 256, 0, stream>>>(
      x, mg, mr, mk, mv, Amg, Amr, Amk, Amv,
      WgW, WrW, WkW, WvW, WoW, WgB, WrB, WkB, WvB, WoB);

  // persistent pair launches: 256 blocks, bx fixed, 4 by-panels/block, 1 round
  gemm256<1,2,4><<<256, 512, 0, stream>>>(Amg, WgB, Wgb, nullptr, gbuf,
                                          Amr, WrB, Wrb, nullptr, rbuf);
  gemm256<1,2,4><<<256, 512, 0, stream>>>(Amk, WkB, Wkb, nullptr, kbuf,
                                          Amv, WvB, Wvb, nullptr, vbuf);

  scan_pass1<<<NB*NCHUNK, 128, 0, stream>>>(kbuf, vbuf, w, chunkAcc);
  scan_pass2<<<NB*NH, 64, 0, stream>>>(chunkAcc, carryPrev, w);
  scan_pass3<<<NB*NCHUNK, 128, 0, stream>>>(kbuf, vbuf, rbuf, gbuf, hbuf, carryPrev, w, u);

  // persistent final GEMM: 256 blocks, 2 by-panels/block, 1 round
  gemm256<0,1,2><<<256, 512, 0, stream>>>(hbuf, WoB, Wob, (float*)d_out, nullptr,
                                          nullptr, nullptr, nullptr, nullptr, nullptr);
}